// Round 8
// baseline (994.654 us; speedup 1.0000x reference)
//
#include <hip/hip_runtime.h>
#include <stdint.h>

typedef __bf16 bf16_t;
typedef bf16_t bf16x8 __attribute__((ext_vector_type(8)));
typedef float f32x4 __attribute__((ext_vector_type(4)));

#define D_DIM 4096   // K
#define O_DIM 4096   // N
#define M_DIM 16384  // M
#define THRESH 0.05f

// ---------- helpers ----------

__device__ __forceinline__ void gld16(const void* g, void* l) {
  __builtin_amdgcn_global_load_lds(
      (const __attribute__((address_space(1))) uint32_t*)(uintptr_t)g,
      (__attribute__((address_space(3))) uint32_t*)(uint32_t)(uintptr_t)l,
      16, 0, 0);
}

__device__ __forceinline__ unsigned short f2bf(float f) {  // RNE f32->bf16
  uint32_t u = __float_as_uint(f);
  u += 0x7FFFu + ((u >> 16) & 1u);
  return (unsigned short)(u >> 16);
}

__device__ __forceinline__ unsigned short tern(float v) {  // bf16 bits of {-1,0,+1}
  return (__builtin_fabsf(v) < THRESH) ? (unsigned short)0
         : (v > 0.f ? (unsigned short)0x3F80 : (unsigned short)0xBF80);
}

// ---------- pre-pass kernels (verified rounds 1-6) ----------

__global__ void k_scale_part(const float* __restrict__ w, float* __restrict__ part) {
  const int cg = blockIdx.x & 63;
  const int dz = blockIdx.x >> 6;
  const int tx = threadIdx.x & 63;
  const int ty = threadIdx.x >> 6;
  const int o = cg * 64 + tx;
  float s = 0.f;
  const float* p = w + (size_t)(dz * 512 + ty) * O_DIM + o;
  for (int i = 0; i < 128; ++i) {
    s += __builtin_fabsf(*p);
    p += 4 * O_DIM;
  }
  __shared__ float red[4][64];
  red[ty][tx] = s;
  __syncthreads();
  if (ty == 0) part[dz * O_DIM + o] = (red[0][tx] + red[1][tx]) + (red[2][tx] + red[3][tx]);
}

__global__ void k_scale_fin(const float* __restrict__ part, float* __restrict__ scale) {
  const int o = blockIdx.x * 256 + threadIdx.x;
  float s = 0.f;
#pragma unroll
  for (int z = 0; z < 8; ++z) s += part[z * O_DIM + o];
  scale[o] = s * (1.0f / 4096.0f);
}

__global__ void k_tern_t(const float* __restrict__ w, unsigned short* __restrict__ bt) {
  __shared__ __align__(16) unsigned short tile[64][68];
  const int ot = blockIdx.x & 63;
  const int dt = blockIdx.x >> 6;
  const int o0 = ot * 64, d0 = dt * 64;
  const int tx = threadIdx.x & 15, ty = threadIdx.x >> 4;
#pragma unroll
  for (int j = 0; j < 4; ++j) {
    const int r = ty + 16 * j;
    const float4 v = *(const float4*)&w[(size_t)(d0 + r) * O_DIM + o0 + tx * 4];
    ushort4 u;
    u.x = tern(v.x); u.y = tern(v.y); u.z = tern(v.z); u.w = tern(v.w);
    *(ushort4*)&tile[r][tx * 4] = u;
  }
  __syncthreads();
#pragma unroll
  for (int j = 0; j < 4; ++j) {
    const int orow = ty + 16 * j;
    ushort4 u;
    u.x = tile[tx * 4 + 0][orow];
    u.y = tile[tx * 4 + 1][orow];
    u.z = tile[tx * 4 + 2][orow];
    u.w = tile[tx * 4 + 3][orow];
    *(ushort4*)&bt[(size_t)(o0 + orow) * D_DIM + d0 + tx * 4] = u;
  }
}

__global__ void k_cvt(const float* __restrict__ x, unsigned short* __restrict__ xb) {
  const size_t i = ((size_t)blockIdx.x * 256 + threadIdx.x) * 8;
  const float4 a = *(const float4*)&x[i];
  const float4 b = *(const float4*)&x[i + 4];
  uint4 o;
  o.x = (uint32_t)f2bf(a.x) | ((uint32_t)f2bf(a.y) << 16);
  o.y = (uint32_t)f2bf(a.z) | ((uint32_t)f2bf(a.w) << 16);
  o.z = (uint32_t)f2bf(b.x) | ((uint32_t)f2bf(b.y) << 16);
  o.w = (uint32_t)f2bf(b.z) | ((uint32_t)f2bf(b.w) << 16);
  *(uint4*)&xb[i] = o;
}

// ---------- 256x256 GEMM: A via LDS (r2/r4 zero-conflict image), B global->VGPR ----------
// C[m][n] = (sum_k A[m][k]*Bt[n][k]) * scale[n] + bias[n]
// BM=BN=256, BK=64, 512 thr = 8 waves (2Mx4N), per-wave C = 128x64, 16x16x32 MFMA.
// LDS 64KB: A only, 2 bufs x [256 rows][64 k] bf16. Image: granule (row,g) at byte
// row*128 + ((g^(row&7))<<4), staged via pre-swizzled GLOBAL src (gld_lds dest linear).
// B: plain C++ 16B loads into bq regs (compiler-tracked waits); panel is L2-resident
// (nb-clustered XCD swizzle: each XCD covers 2 panels = 4MB).
// Calendar per tile T (buf d = T&1); aqA/aqB were PRE-READ during tile T-1:
//   p0: issue LOADB(T) (8 vmem) + STAGE(d, T+2) (4 gld_lds); BAR1;
//       vmcnt(4)  [queue: st(T+1)(4) bq(T)(8) st(T+2)(4) -> forces st(T+1)+bq(T)]
//       lgkmcnt(0) [aqA/aqB pre-reads done]; MM(kk0, aqA)
//   p1: BAR2; RA(d^1, 0 -> aqA); MM(kk1, aqB); RA(d^1, 1 -> aqB); BAR3
// Stage-overwrite safety: buf d's frag reads happened tile T-1 p1, >=2 barriers
// before STAGE(d) issues (stronger than r4's verified 1-barrier windows).

#define BAR() __builtin_amdgcn_s_barrier()
#define SB0() __builtin_amdgcn_sched_barrier(0)
#define LGKM(n) asm volatile("s_waitcnt lgkmcnt(" #n ")" ::: "memory")
#define VMW(n) asm volatile("s_waitcnt vmcnt(" #n ")" ::: "memory")

#define STAGE(d, kv)                                                   \
  do {                                                                 \
    gld16(pA0 + (kv)*64, smem + (d)*32768 + t * 16);                   \
    gld16(pA1 + (kv)*64, smem + (d)*32768 + 8192 + t * 16);            \
    gld16(pA2 + (kv)*64, smem + (d)*32768 + 16384 + t * 16);           \
    gld16(pA3 + (kv)*64, smem + (d)*32768 + 24576 + t * 16);           \
  } while (0)

#define RA(d, kk, AQ)                                                  \
  do {                                                                 \
    const char* q_ = smem + (d)*32768 + wr * 16384 + r16 * 128 +       \
                     (slot0 ^ ((kk)*64));                              \
    _Pragma("unroll") for (int m = 0; m < 8; ++m)                      \
        AQ[m] = *(const bf16x8*)(q_ + m * 2048);                       \
  } while (0)

#define LOADB(ktv)                                                     \
  do {                                                                 \
    const char* b0_ = bgB + (ktv)*128;                                 \
    _Pragma("unroll") for (int n = 0; n < 4; ++n) {                    \
      bq[0][n] = *(const bf16x8*)(b0_ + n * 131072);                   \
      bq[1][n] = *(const bf16x8*)(b0_ + n * 131072 + 64);              \
    }                                                                  \
  } while (0)

#define MM(kk, AQ)                                                            \
  do {                                                                        \
    __builtin_amdgcn_s_setprio(1);                                            \
    _Pragma("unroll") for (int m = 0; m < 8; ++m)                             \
    _Pragma("unroll") for (int n = 0; n < 4; ++n)                             \
        acc[m][n] = __builtin_amdgcn_mfma_f32_16x16x32_bf16(                  \
            AQ[m], bq[kk][n], acc[m][n], 0, 0, 0);                            \
    __builtin_amdgcn_s_setprio(0);                                            \
  } while (0)

#define TILE(d, ktB, kS)                                                 \
  do {                                                                   \
    LOADB(ktB);                                                          \
    STAGE(d, kS);                                                        \
    SB0(); BAR();                                                        \
    VMW(4); LGKM(0); SB0();                                              \
    MM(0, aqA);                                                          \
    BAR();                                                               \
    RA((d) ^ 1, 0, aqA);                                                 \
    MM(1, aqB);                                                          \
    RA((d) ^ 1, 1, aqB);                                                 \
    SB0(); BAR();                                                        \
  } while (0)

__global__ __launch_bounds__(512, 2) void k_gemm8(
    const unsigned short* __restrict__ A,   // [M][K] bf16 bits
    const unsigned short* __restrict__ B,   // [N][K] bf16 bits (ternary)
    const float* __restrict__ scale, const float* __restrict__ bias,
    float* __restrict__ C) {
  __shared__ __align__(16) char smem[65536];

  // nb-clustered XCD swizzle: each XCD handles 2 B panels (4MB, L2-resident)
  const int bid = blockIdx.x;
  const int wg = (bid & 7) * 128 + (bid >> 3);
  const int nb = wg >> 6, mb = wg & 63;  // 16 x 64 blocks
  const int mBase = mb * 256, nBase = nb * 256;

  const int t = threadIdx.x;
  const int lane = t & 63, wid = t >> 6;
  const int wr = wid >> 2, wc = wid & 3;  // 2 x 4 waves
  const int r16 = lane & 15, kq = lane >> 4;

  // A read addressing (verified zero-conflict 16x16 pattern, r2/r4)
  const int slot0 = (kq ^ (r16 & 7)) << 4;

  // A staging: thread t stages granules t, t+512, t+1024, t+1536 per tile
  const int sr0 = t >> 3, sg0 = (t & 7) ^ (sr0 & 7);
  const unsigned short* pA0 = A + (size_t)(mBase + sr0) * D_DIM + sg0 * 8;
  const unsigned short* pA1 = pA0 + (size_t)64 * D_DIM;
  const unsigned short* pA2 = pA0 + (size_t)128 * D_DIM;
  const unsigned short* pA3 = pA0 + (size_t)192 * D_DIM;

  // B per-lane byte base; frag (n,kk,tile T): + n*131072 + kk*64 + T*128
  const char* bgB = (const char*)B +
      ((size_t)(nBase + wc * 64 + r16) * D_DIM + kq * 8) * 2;

  f32x4 acc[8][4] = {};
  bf16x8 aqA[8], aqB[8];  // current tile's A fragments (kk=0 / kk=1)
  bf16x8 bq[2][4];        // current tile's B fragments [kk][n]

  // prologue: stage tile0->buf0, tile1->buf1; force tile0; pre-read tile0 frags
  STAGE(0, 0);
  STAGE(1, 1);
  VMW(4);  // queue [st0(4), st1(4)] -> forces st0
  BAR();
  RA(0, 0, aqA);
  RA(0, 1, aqB);

  for (int T = 0; T < 64; T += 2) {
    TILE(0, T, (T + 2) & 63);      // tiles 62/63 stage valid dummies (never read)
    TILE(1, T + 1, (T + 3) & 63);
  }
  VMW(0);  // drain dummy stages before exit

  // epilogue: C/D mapping col=lane&15, row=4*(lane>>4)+r (verified r1/r2/r4)
#pragma unroll
  for (int n = 0; n < 4; ++n) {
    const int gc = nBase + wc * 64 + n * 16 + r16;
    const float sc = scale[gc];
    const float bb = bias[gc];
#pragma unroll
    for (int m = 0; m < 8; ++m) {
      const int gr0 = mBase + wr * 128 + m * 16 + kq * 4;
#pragma unroll
      for (int r = 0; r < 4; ++r) {
        C[(size_t)(gr0 + r) * O_DIM + gc] = acc[m][n][r] * sc + bb;
      }
    }
  }
}

// ---------- launch ----------

extern "C" void kernel_launch(void* const* d_in, const int* in_sizes, int n_in,
                              void* d_out, int out_size, void* d_ws, size_t ws_size,
                              hipStream_t stream) {
  const float* x = (const float*)d_in[0];
  const float* w = (const float*)d_in[1];
  const float* bias = (const float*)d_in[2];
  float* out = (float*)d_out;

  const size_t XB_OFF = 0;
  const size_t BT_OFF = (size_t)M_DIM * D_DIM * 2;
  const size_t PART_OFF = BT_OFF + (size_t)O_DIM * D_DIM * 2;
  const size_t SCALE_OFF = PART_OFF + 8 * O_DIM * 4;
  const size_t NEED = SCALE_OFF + O_DIM * 4;
  if (ws_size < NEED) return;

  char* ws = (char*)d_ws;
  unsigned short* xb = (unsigned short*)(ws + XB_OFF);
  unsigned short* bt = (unsigned short*)(ws + BT_OFF);
  float* part = (float*)(ws + PART_OFF);
  float* scale = (float*)(ws + SCALE_OFF);

  k_scale_part<<<512, 256, 0, stream>>>(w, part);
  k_scale_fin<<<16, 256, 0, stream>>>(part, scale);
  k_tern_t<<<64 * 64, 256, 0, stream>>>(w, bt);
  k_cvt<<<(M_DIM * (D_DIM / 8)) / 256, 256, 0, stream>>>(x, xb);
  k_gemm8<<<1024, 512, 0, stream>>>(xb, bt, scale, bias, out);
}

// Round 9
// 373.503 us; speedup vs baseline: 2.6630x; 2.6630x over previous
//
#include <hip/hip_runtime.h>
#include <stdint.h>

typedef int i32x4 __attribute__((ext_vector_type(4)));

#define D_DIM 4096   // K
#define O_DIM 4096   // N
#define M_DIM 16384  // M
#define THRESH 0.05f

// ---------- helpers ----------

__device__ __forceinline__ void gld16(const void* g, void* l) {
  __builtin_amdgcn_global_load_lds(
      (const __attribute__((address_space(1))) uint32_t*)(uintptr_t)g,
      (__attribute__((address_space(3))) uint32_t*)(uint32_t)(uintptr_t)l,
      16, 0, 0);
}

__device__ __forceinline__ int tern_i8(float v) {  // {-1,0,+1} as signed byte
  return (__builtin_fabsf(v) < THRESH) ? 0 : (v > 0.f ? 1 : -1);
}

// ---------- pre-pass kernels ----------

// column-scale partials (verified r1-r8)
__global__ void k_scale_part(const float* __restrict__ w, float* __restrict__ part) {
  const int cg = blockIdx.x & 63;
  const int dz = blockIdx.x >> 6;
  const int tx = threadIdx.x & 63;
  const int ty = threadIdx.x >> 6;
  const int o = cg * 64 + tx;
  float s = 0.f;
  const float* p = w + (size_t)(dz * 512 + ty) * O_DIM + o;
  for (int i = 0; i < 128; ++i) {
    s += __builtin_fabsf(*p);
    p += 4 * O_DIM;
  }
  __shared__ float red[4][64];
  red[ty][tx] = s;
  __syncthreads();
  if (ty == 0) part[dz * O_DIM + o] = (red[0][tx] + red[1][tx]) + (red[2][tx] + red[3][tx]);
}

__global__ void k_scale_fin(const float* __restrict__ part, float* __restrict__ scale) {
  const int o = blockIdx.x * 256 + threadIdx.x;
  float s = 0.f;
#pragma unroll
  for (int z = 0; z < 8; ++z) s += part[z * O_DIM + o];
  scale[o] = s * (1.0f / 4096.0f);
}

// ternarize + transpose: w[d][o] f32 -> btq[o][d] i8 in {-1,0,1}; 64x64 tiles
__global__ void k_tern_q(const float* __restrict__ w, char* __restrict__ btq) {
  __shared__ char tile[64][68];
  const int ot = blockIdx.x & 63;
  const int dt = blockIdx.x >> 6;
  const int o0 = ot * 64, d0 = dt * 64;
  const int tx = threadIdx.x & 15, ty = threadIdx.x >> 4;
#pragma unroll
  for (int j = 0; j < 4; ++j) {
    const int r = ty + 16 * j;  // d_local
    const float4 v = *(const float4*)&w[(size_t)(d0 + r) * O_DIM + o0 + tx * 4];
    uint32_t u = (uint32_t)(tern_i8(v.x) & 0xFF) |
                 ((uint32_t)(tern_i8(v.y) & 0xFF) << 8) |
                 ((uint32_t)(tern_i8(v.z) & 0xFF) << 16) |
                 ((uint32_t)(tern_i8(v.w) & 0xFF) << 24);
    *(uint32_t*)&tile[r][tx * 4] = u;
  }
  __syncthreads();
#pragma unroll
  for (int j = 0; j < 4; ++j) {
    const int orow = ty + 16 * j;  // o_local
    uint32_t u = (uint32_t)((uint8_t)tile[tx * 4 + 0][orow]) |
                 ((uint32_t)((uint8_t)tile[tx * 4 + 1][orow]) << 8) |
                 ((uint32_t)((uint8_t)tile[tx * 4 + 2][orow]) << 16) |
                 ((uint32_t)((uint8_t)tile[tx * 4 + 3][orow]) << 24);
    *(uint32_t*)&btq[(size_t)(o0 + orow) * D_DIM + d0 + tx * 4] = u;
  }
}

// x f32 -> i8 with per-row symmetric scale (rowmax/127); one block per row
__global__ void k_quant(const float* __restrict__ x, char* __restrict__ xq,
                        float* __restrict__ sx) {
  const int row = blockIdx.x;
  const int t = threadIdx.x;  // 256
  const float* xr = x + (size_t)row * D_DIM + t * 16;
  float4 v[4];
#pragma unroll
  for (int i = 0; i < 4; ++i) v[i] = *(const float4*)(xr + i * 4);
  float m = 0.f;
#pragma unroll
  for (int i = 0; i < 4; ++i) {
    m = fmaxf(m, fmaxf(fmaxf(__builtin_fabsf(v[i].x), __builtin_fabsf(v[i].y)),
                       fmaxf(__builtin_fabsf(v[i].z), __builtin_fabsf(v[i].w))));
  }
#pragma unroll
  for (int off = 32; off >= 1; off >>= 1) m = fmaxf(m, __shfl_xor(m, off, 64));
  __shared__ float wm[4];
  if ((t & 63) == 0) wm[t >> 6] = m;
  __syncthreads();
  const float rm = fmaxf(fmaxf(wm[0], wm[1]), fmaxf(wm[2], wm[3]));
  const float inv = (rm > 0.f) ? 127.0f / rm : 0.0f;
  int4 o;
  int* op = (int*)&o;
#pragma unroll
  for (int i = 0; i < 4; ++i) {
    const float* f = (const float*)&v[i];
    uint32_t u = 0;
#pragma unroll
    for (int j = 0; j < 4; ++j) {
      float q = __builtin_rintf(f[j] * inv);
      q = fmaxf(-127.f, fminf(127.f, q));
      u |= ((uint32_t)((int)q & 0xFF)) << (8 * j);
    }
    op[i] = (int)u;
  }
  *(int4*)(xq + (size_t)row * D_DIM + t * 16) = o;
  if (t == 0) sx[row] = (rm > 0.f) ? rm * (1.0f / 127.0f) : 0.0f;
}

// ---------- 256x256 i8 GEMM, BK=128, r4 calendar + r4 LDS image (byte-identical) ----------
// acc_i32[m][n] = sum_k xq[m][k]*btq[n][k];  C = float(acc)*(sx[m]*scale[n]) + bias[n]
// 512 thr = 8 waves (2Mx4N), per-wave C = 128x64, mfma_i32_16x16x64_i8 (A/B 16B/lane).
// LDS 128KB: A = [buf2][half2][128 rows][128B]; B same at +64KB — same bytes as r4.
// Image: granule (row,g) at byte row*128 + ((g^(row&7))<<4) (measured zero-conflict).
// i8 frag: lane l reads row = base+(l&15), k-granule = (l>>4) + 4*kk -> slot kq^r7,
// (kq^r7)^4 == aLane, aLane^64 — bit-identical addressing to r4.
// Calendar per tile T (buf d = T&1), stages target T+2 -> buf d (r4, 460us-verified):
//   p0: READ_A(d,0) | STAGE_B(d,0) | BAR lgkm0 MQ(0,0) BAR
//   p1: READ_A(d,1) | STAGE_B(d,1) | BAR lgkm0 MQ(0,1) BAR
//   p2:             | STAGE_A(d,0) | BAR      MQ(1,0) VMW(10) BAR
//   p3: READ_B(d^1) | STAGE_A(d,1) | BAR      MQ(1,1) VMW(8)  BAR

#define BAR() __builtin_amdgcn_s_barrier()
#define SB0() __builtin_amdgcn_sched_barrier(0)
#define LGKM0()                                         \
  do {                                                  \
    asm volatile("s_waitcnt lgkmcnt(0)" ::: "memory");  \
    __builtin_amdgcn_sched_barrier(0);                  \
  } while (0)
#define VMW(n) asm volatile("s_waitcnt vmcnt(" #n ")" ::: "memory")

#define STAGE_A(d, h, kv)                                                    \
  do {                                                                       \
    gld16(pA##h##_0 + (size_t)(kv) * 128,                                    \
          smem + (d)*32768 + (h)*16384 + t * 16);                            \
    gld16(pA##h##_1 + (size_t)(kv) * 128,                                    \
          smem + (d)*32768 + (h)*16384 + 8192 + t * 16);                     \
  } while (0)
#define STAGE_B(d, h, kv)                                                    \
  do {                                                                       \
    gld16(pB##h##_0 + (size_t)(kv) * 128,                                    \
          smem + 65536 + (d)*32768 + (h)*16384 + t * 16);                    \
    gld16(pB##h##_1 + (size_t)(kv) * 128,                                    \
          smem + 65536 + (d)*32768 + (h)*16384 + 8192 + t * 16);             \
  } while (0)

#define READ_A(d, mh)                                                   \
  do {                                                                  \
    const char* ab_ = smem + (d)*32768 + wr * 16384 + (mh)*8192;        \
    _Pragma("unroll") for (int m4 = 0; m4 < 4; ++m4) {                  \
      aq[mh][0][m4] = *(const i32x4*)(ab_ + m4 * 2048 + aLane);         \
      aq[mh][1][m4] = *(const i32x4*)(ab_ + m4 * 2048 + (aLane ^ 64));  \
    }                                                                   \
  } while (0)

#define READ_B(db, pp)                                                       \
  do {                                                                       \
    const char* bb_ = smem + 65536 + (db)*32768 + hb * 16384 + hw8192;       \
    _Pragma("unroll") for (int nh = 0; nh < 2; ++nh)                         \
    _Pragma("unroll") for (int n2 = 0; n2 < 2; ++n2) {                       \
      bq[pp][nh][0][n2] =                                                    \
          *(const i32x4*)(bb_ + nh * 4096 + n2 * 2048 + aLane);              \
      bq[pp][nh][1][n2] =                                                    \
          *(const i32x4*)(bb_ + nh * 4096 + n2 * 2048 + (aLane ^ 64));       \
    }                                                                        \
  } while (0)

#define MQ(mh, nh, pp)                                                        \
  do {                                                                        \
    __builtin_amdgcn_s_setprio(1);                                            \
    _Pragma("unroll") for (int kk = 0; kk < 2; ++kk)                          \
    _Pragma("unroll") for (int m4 = 0; m4 < 4; ++m4)                          \
    _Pragma("unroll") for (int n2 = 0; n2 < 2; ++n2)                          \
        acc[(mh)*4 + m4][(nh)*2 + n2] =                                       \
            __builtin_amdgcn_mfma_i32_16x16x64_i8(                            \
                aq[mh][kk][m4], bq[pp][nh][kk][n2],                           \
                acc[(mh)*4 + m4][(nh)*2 + n2], 0, 0, 0);                      \
    __builtin_amdgcn_s_setprio(0);                                            \
  } while (0)

#define TILE(d, pp, kv)                                                  \
  do {                                                                   \
    READ_A(d, 0); STAGE_B(d, 0, kv);                                     \
    BAR(); LGKM0(); MQ(0, 0, pp); BAR();                                 \
    READ_A(d, 1); STAGE_B(d, 1, kv);                                     \
    BAR(); LGKM0(); MQ(0, 1, pp); BAR();                                 \
    STAGE_A(d, 0, kv);                                                   \
    BAR(); __builtin_amdgcn_sched_barrier(0); MQ(1, 0, pp); VMW(10);     \
    BAR();                                                               \
    READ_B((d) ^ 1, (pp) ^ 1); STAGE_A(d, 1, kv);                        \
    BAR(); __builtin_amdgcn_sched_barrier(0); MQ(1, 1, pp); VMW(8);      \
    BAR();                                                               \
  } while (0)

__global__ __launch_bounds__(512, 2) void k_gemm8(
    const char* __restrict__ A,   // xq [M][K] i8
    const char* __restrict__ B,   // btq [N][K] i8 (ternary)
    const float* __restrict__ sx, const float* __restrict__ scale,
    const float* __restrict__ bias, float* __restrict__ C) {
  __shared__ __align__(16) char smem[131072];

  const int bid = blockIdx.x;
  const int wg = (bid & 7) * 128 + (bid >> 3);  // XCD swizzle, 1024%8==0
  const int mb = wg >> 4, nb = wg & 15;         // 64 x 16 blocks
  const int mBase = mb * 256, nBase = nb * 256;

  const int t = threadIdx.x;
  const int lane = t & 63, wid = t >> 6;
  const int wr = wid >> 2, wc = wid & 3;  // 2 x 4 waves
  const int hb = wc >> 1;                 // B row-half this wave reads
  const int hw8192 = (wc & 1) * 8192;
  const int r16 = lane & 15, kq = lane >> 4;
  const int aLane = r16 * 128 + ((kq ^ (lane & 7)) << 4);

  // staging: thread t stages granules q0=t, q1=512+t of each 16KB half-tile
  const int q1 = 512 + t;
  const int sr0 = t >> 3, sg0 = (t & 7) ^ (sr0 & 7);
  const int sr1 = q1 >> 3, sg1 = (q1 & 7) ^ (sr1 & 7);

  const char* pA0_0 = A + (size_t)(mBase + sr0) * D_DIM + sg0 * 16;
  const char* pA0_1 = A + (size_t)(mBase + sr1) * D_DIM + sg1 * 16;
  const char* pA1_0 = A + (size_t)(mBase + 128 + sr0) * D_DIM + sg0 * 16;
  const char* pA1_1 = A + (size_t)(mBase + 128 + sr1) * D_DIM + sg1 * 16;
  const char* pB0_0 = B + (size_t)(nBase + sr0) * D_DIM + sg0 * 16;
  const char* pB0_1 = B + (size_t)(nBase + sr1) * D_DIM + sg1 * 16;
  const char* pB1_0 = B + (size_t)(nBase + 128 + sr0) * D_DIM + sg0 * 16;
  const char* pB1_1 = B + (size_t)(nBase + 128 + sr1) * D_DIM + sg1 * 16;

  i32x4 acc[8][4] = {};
  i32x4 aq[2][2][4];     // [mh][kk][m4]
  i32x4 bq[2][2][2][2];  // [parity][nh][kk][n2]

  // prologue: tile0 -> buf0, tile1 -> buf1; force tile0; pre-read bq(tile0)
  STAGE_B(0, 0, 0); STAGE_B(0, 1, 0); STAGE_A(0, 0, 0); STAGE_A(0, 1, 0);
  STAGE_B(1, 0, 1); STAGE_B(1, 1, 1); STAGE_A(1, 0, 1); STAGE_A(1, 1, 1);
  VMW(8);  // tile0's 8 ops landed
  BAR();
  RB_PROLOGUE:;
  READ_B(0, 0);
  LGKM0();  // bq(tile0) in regs before any later overwrite can land
  BAR();

  for (int T = 0; T < 32; T += 2) {
    TILE(0, 0, (T + 2) & 31);  // tiles 30/31 stage dummy wrap (never read)
    TILE(1, 1, (T + 3) & 31);
  }
  VMW(0);  // drain dummy stages

  // epilogue: C/D mapping col=lane&15, row=4*(lane>>4)+r (dtype-independent, verified)
  float sxr[8][4];
#pragma unroll
  for (int mi = 0; mi < 8; ++mi) {
    const int gr0 = mBase + wr * 128 + mi * 16 + kq * 4;
#pragma unroll
    for (int r = 0; r < 4; ++r) sxr[mi][r] = sx[gr0 + r];
  }
#pragma unroll
  for (int ni = 0; ni < 4; ++ni) {
    const int gc = nBase + wc * 64 + ni * 16 + r16;
    const float sw = scale[gc];
    const float bb = bias[gc];
#pragma unroll
    for (int mi = 0; mi < 8; ++mi) {
      const int gr0 = mBase + wr * 128 + mi * 16 + kq * 4;
#pragma unroll
      for (int r = 0; r < 4; ++r) {
        C[(size_t)(gr0 + r) * O_DIM + gc] =
            (float)acc[mi][ni][r] * (sxr[mi][r] * sw) + bb;
      }
    }
  }
}

// ---------- launch ----------

extern "C" void kernel_launch(void* const* d_in, const int* in_sizes, int n_in,
                              void* d_out, int out_size, void* d_ws, size_t ws_size,
                              hipStream_t stream) {
  const float* x = (const float*)d_in[0];
  const float* w = (const float*)d_in[1];
  const float* bias = (const float*)d_in[2];
  float* out = (float*)d_out;

  const size_t XQ_OFF = 0;                                    // 64MB
  const size_t BT_OFF = (size_t)M_DIM * D_DIM;                // +16MB
  const size_t SX_OFF = BT_OFF + (size_t)O_DIM * D_DIM;       // +64KB
  const size_t PART_OFF = SX_OFF + (size_t)M_DIM * 4;
  const size_t SCALE_OFF = PART_OFF + 8 * O_DIM * 4;
  const size_t NEED = SCALE_OFF + O_DIM * 4;
  if (ws_size < NEED) return;

  char* ws = (char*)d_ws;
  char* xq = ws + XQ_OFF;
  char* btq = ws + BT_OFF;
  float* sx = (float*)(ws + SX_OFF);
  float* part = (float*)(ws + PART_OFF);
  float* scale = (float*)(ws + SCALE_OFF);

  k_scale_part<<<512, 256, 0, stream>>>(w, part);
  k_scale_fin<<<16, 256, 0, stream>>>(part, scale);
  k_tern_q<<<64 * 64, 256, 0, stream>>>(w, btq);
  k_quant<<<M_DIM, 256, 0, stream>>>(x, xq, sx);
  k_gemm8<<<1024, 512, 0, stream>>>(xq, btq, sx, scale, bias, out);
}